// Round 4
// baseline (484.375 us; speedup 1.0000x reference)
//
#include <hip/hip_runtime.h>

typedef unsigned short ushort_t;
typedef unsigned int uint_t;
typedef __bf16 bf16x8 __attribute__((ext_vector_type(8)));
typedef float float4v __attribute__((ext_vector_type(4)));
typedef uint_t uint4v __attribute__((ext_vector_type(4)));
typedef uint_t uint2v __attribute__((ext_vector_type(2)));

#define EPS 1e-6f

// Workspace layout (bytes)
#define WS_STYLE   0            // 16*512 f32 = 32 KB
#define WS_INVD    32768        // 16*512 f32 = 32 KB
#define WS_WSQ     65536        // 512*512 f32 = 1 MB
#define WS_AW      1114112      // 512*4608 bf16 = 4,718,592 B
#define WS_XP      6291456      // 16*66*66*512 bf16 = 71,368,704 B

__device__ __forceinline__ ushort_t f2bf(float v) {
    union { float f; uint_t u; } c; c.f = v;
    uint_t u = c.u;
    u += 0x7fffu + ((u >> 16) & 1u);   // round-to-nearest-even
    return (ushort_t)(u >> 16);
}

__device__ __forceinline__ void gload_lds16(const void* g, void* l) {
    __builtin_amdgcn_global_load_lds(
        (const __attribute__((address_space(1))) uint_t*)g,
        (__attribute__((address_space(3))) uint_t*)l, 16, 0, 0);
}

// ---------------- L1 (fused): style GEMV + weight cast/permute ----------------
__global__ void prep_fused1(const float* __restrict__ w, const float* __restrict__ lw,
                            const float* __restrict__ lb, const float* __restrict__ cw,
                            float* __restrict__ style, ushort_t* __restrict__ Aw,
                            float* __restrict__ wsq) {
    int blk = blockIdx.x;
    if (blk < 2048) {
        int gw = blk * 4 + (threadIdx.x >> 6);   // 0..8191
        int lane = threadIdx.x & 63;
        int b = gw >> 9, o = gw & 511;
        float s = 0.f;
#pragma unroll
        for (int j = 0; j < 8; ++j) {
            int d = j * 64 + lane;
            s += w[b * 512 + d] * lw[o * 512 + d];
        }
#pragma unroll
        for (int off = 32; off; off >>= 1) s += __shfl_down(s, off);
        if (lane == 0) style[gw] = s + lb[o];
    } else {
        int id = (blk - 2048) * 256 + threadIdx.x;   // o*512 + i
        int o = id >> 9, i = id & 511;
        const float* p = cw + (size_t)id * 9;
        size_t base = (size_t)o * 4608 + (size_t)(i >> 6) * 576 + (i & 63);
        float s = 0.f;
#pragma unroll
        for (int t = 0; t < 9; ++t) {
            float v = p[t];
            s += v * v;
            Aw[base + t * 64] = f2bf(v);
        }
        wsq[id] = s;
    }
}

// ---------------- L2 (fused): inv_denom + border zero + modulate/transpose ----------------
__global__ void prep_fused2(const float* __restrict__ wsq, const float* __restrict__ style,
                            float* __restrict__ invd, const float* __restrict__ x,
                            ushort_t* __restrict__ Xp) {
    __shared__ ushort_t tile[64][66];   // modulate branch only
    int blk = blockIdx.x;
    if (blk < 2048) {
        // invd[b][o] = rsqrt(sum_i wsq[o][i]*style[b][i]^2 + eps)
        int gw = blk * 4 + (threadIdx.x >> 6);
        int lane = threadIdx.x & 63;
        int b = gw >> 9, o = gw & 511;
        float s = 0.f;
#pragma unroll
        for (int j = 0; j < 8; ++j) {
            int d = j * 64 + lane;
            float st = style[b * 512 + d];
            s += wsq[o * 512 + d] * st * st;
        }
#pragma unroll
        for (int off = 32; off; off >>= 1) s += __shfl_down(s, off);
        if (lane == 0) invd[gw] = rsqrtf(s + EPS);
    } else if (blk < 3088) {
        // zero the 1-px padding border of Xp (NHWC, 66x66); 4 border-pixels/block
        int j = (blk - 2048) * 4 + (threadIdx.x >> 6);   // 0..4159
        int lane = threadIdx.x & 63;
        int b = j / 260, bp = j - b * 260;
        int py, px;
        if (bp < 66)       { py = 0;        px = bp; }
        else if (bp < 132) { py = 65;       px = bp - 66; }
        else if (bp < 196) { py = bp - 131; px = 0; }
        else               { py = bp - 195; px = 65; }
        size_t pix = ((size_t)b * 66 + py) * 66 + px;
        ((uint4v*)(Xp + pix * 512))[lane] = (uint4v){0, 0, 0, 0};
    } else {
        // Xp[b][y+1][x+1][i] = bf16(x[b][i][y][x] * style[b][i])  (NHWC interior)
        int mb = blk - 3088;          // 0..8191
        int y = mb & 63;
        int chunk = mb >> 6;          // 0..127
        int i0 = (chunk & 7) * 64;
        int b = chunk >> 3;
        int tid = threadIdx.x;
        int ch = tid >> 2;            // 0..63 channel within tile
        int xq = tid & 3;             // x-quarter slot
        float s = style[b * 512 + i0 + ch];
        const float* xrow = x + (((size_t)b * 512 + i0 + ch) * 64 + y) * 64;
#pragma unroll
        for (int pass = 0; pass < 4; ++pass) {
            int x0 = pass * 16 + xq * 4;
            float4v v = *(const float4v*)(xrow + x0);
            ushort_t u[4];
#pragma unroll
            for (int j = 0; j < 4; ++j) u[j] = f2bf(v[j] * s);
            *(uint2v*)(&tile[ch][x0]) = *(const uint2v*)u;
        }
        __syncthreads();
        size_t rowbase = ((size_t)b * 66 + (y + 1)) * 66 + 1;
#pragma unroll
        for (int pass = 0; pass < 2; ++pass) {
            int idx = pass * 256 + tid;
            int xx = idx >> 3;        // 0..63
            int ch8 = idx & 7;        // 8-channel chunk
            ushort_t v[8];
#pragma unroll
            for (int j = 0; j < 8; ++j) v[j] = tile[ch8 * 8 + j][xx];
            *(uint4v*)(Xp + (rowbase + xx) * 512 + i0 + ch8 * 8) = *(uint4v*)v;
        }
    }
}

// ---------------- Main implicit-GEMM conv: per batch M=512, N=4096, K=4608 ----------------
// 256x256 tile, BK=64, 512 threads (8 waves, 2M x 4N), per-wave 128x64 output.
// QUADRANT-PHASED K-tile (4 phases of 16 MFMA). Each phase: issue next quadrant's
// 4-8 ds_read_b128 into ping-pong frag buffers (aC/aN, bC/bN: <=16 live frags,
// 64 VGPR) then 16 MFMA on already-loaded frags; sched_barrier(0) pins reads ABOVE
// each MFMA cluster so the compiler cannot sink them (r3's 24-live-frag regions
// made the pressure-driven scheduler serialize reads with MFMAs: 4433 cyc/K-tile
// ~= 2483 MFMA + 1950 LDS, i.e. zero overlap).
// Sync per K-tile (unchanged from r3): 1 lgkmcnt(0) + 1 vmcnt(0) (only stage(kt+1),
// issued 2 K-tiles earlier, is outstanding -> counted-in-spirit) + 1 barrier; stage
// (kt+2) right after the barrier that frees its buffer; cross-buffer reads only
// after the certifying barrier (per-wave vmcnt + barrier = race-free).
// K order channel-block-outer/tap-inner (L2-resident B); XCD remap: one batch per
// XCD concurrent. LDS granule-slot XOR swizzle (0 bank conflicts measured).
__global__ __launch_bounds__(512, 2) void conv_gemm(const ushort_t* __restrict__ Aw,
                                                    const ushort_t* __restrict__ Xp,
                                                    const float* __restrict__ invd,
                                                    float* __restrict__ out) {
    __shared__ ushort_t lds[2][32768];   // per buf: A [0,32KB), B [32KB,64KB)

    const int tid  = threadIdx.x;
    const int lane = tid & 63;
    const int wv   = tid >> 6;      // 0..7
    const int wm   = wv >> 2;       // 0..1  (M half)
    const int wn   = wv & 3;        // 0..3  (N quarter)
    const int l15  = lane & 15;
    const int quad = lane >> 4;

    // XCD-aware bijective remap: one batch concurrent per XCD.
    const int bid = blockIdx.x;
    const int xcd = bid & 7;
    const int ci  = bid >> 3;
    const int b   = xcd * 2 + (ci >> 5);
    const int ot  = (ci >> 4) & 1;
    const int pxt = ci & 15;
    const int o0  = ot * 256;
    const int p0  = pxt * 256;

    // staging: thread tid covers granule q = s*512+tid; row = s*64+(tid>>3),
    // stored slot = tid&7, source granule = slot ^ (row&7)
    const int tr  = tid >> 3;                           // 0..63
    const int gsw = (((tid & 7) ^ (tr & 7)) << 4);
    const char* aga0 = (const char*)Aw + (size_t)(o0 + tr) * 9216 + gsw;
    const char* bga0 = (const char*)Xp + ((size_t)(b * 66 + pxt * 4) * 66 + tr) * 1024 + gsw;
    const int lds_wv = wv * 1024;

    // read-side (frag) addresses
    const int sw0 = ((quad ^ (l15 & 7)) << 4);          // k-slice 0 granules 0..3
    const int sw1 = (((4 + quad) ^ (l15 & 7)) << 4);    // k-slice 1 granules 4..7
    const int aoffs = (wm * 128 + l15) * 128;           // + mi*2048
    const int boffs = 32768 + (wn * 64 + l15) * 128;    // + ni*2048

    float4v acc[8][4] = {};
    bf16x8 aC[4], aN[4], bC[4], bN[4];

    auto stage = [&](int kt2) {
        const int parity = kt2 & 1;
        const long aoff = (long)kt2 * 128;
        const int iblk = (kt2 * 7282) >> 16;            // floor(kt2/9)
        const int t = kt2 - iblk * 9;
        const int dh = t / 3, dw = t - dh * 3;
        const long boff = (long)(dh * 66 + dw) * 1024 + (long)iblk * 128;
        char* la = (char*)&lds[parity][0]     + lds_wv;
        char* lb = (char*)&lds[parity][16384] + lds_wv;
#pragma unroll
        for (int s = 0; s < 4; ++s) {
            gload_lds16(aga0 + (size_t)s * 589824 + aoff, la + s * 8192);
            gload_lds16(bga0 + (size_t)s * 67584  + boff, lb + s * 8192);
        }
    };

    auto RD_A = [&](bf16x8 (&av)[4], const char* base, int h, int sw) {
#pragma unroll
        for (int j = 0; j < 4; ++j)
            av[j] = *(const bf16x8*)(base + aoffs + (h * 4 + j) * 2048 + sw);
    };
    auto RD_B = [&](bf16x8 (&bv)[4], const char* base, int sw) {
#pragma unroll
        for (int j = 0; j < 4; ++j)
            bv[j] = *(const bf16x8*)(base + boffs + j * 2048 + sw);
    };
    auto MFMA16 = [&](bf16x8 (&av)[4], bf16x8 (&bv)[4], int h) {
        __builtin_amdgcn_s_setprio(1);
#pragma unroll
        for (int mi = 0; mi < 4; ++mi)
#pragma unroll
            for (int ni = 0; ni < 4; ++ni)
                acc[h * 4 + mi][ni] =
                    __builtin_amdgcn_mfma_f32_16x16x32_bf16(av[mi], bv[ni], acc[h * 4 + mi][ni], 0, 0, 0);
        __builtin_amdgcn_s_setprio(0);
    };

    // prologue: prime 2 K-tiles, certify tile 0, preload Q0 frags
    stage(0);
    stage(1);
    asm volatile("s_waitcnt vmcnt(0)" ::: "memory");
    __builtin_amdgcn_s_barrier();
    {
        const char* b0p = (const char*)&lds[0][0];
        RD_A(aC, b0p, 0, sw0);
        RD_B(bC, b0p, sw0);
    }

#pragma unroll 1
    for (int kt = 0; kt < 72; ++kt) {
        const char* cb = (const char*)&lds[kt & 1][0];

        // ph0: read Q1 frags || MFMA Q0 (mi0-3, ks0)
        RD_A(aN, cb, 1, sw0);
        __builtin_amdgcn_sched_barrier(0);
        MFMA16(aC, bC, 0);

        // ph1: read Q2 frags || MFMA Q1 (mi4-7, ks0)
        RD_A(aC, cb, 0, sw1);
        RD_B(bN, cb, sw1);
        __builtin_amdgcn_sched_barrier(0);
        MFMA16(aN, bC, 1);

        // ph2: read Q3 frags || MFMA Q2 (mi0-3, ks1)
        RD_A(aN, cb, 1, sw1);
        __builtin_amdgcn_sched_barrier(0);
        MFMA16(aC, bN, 0);

        // ph3: certify + swap buffers + stage + preload next Q0 || MFMA Q3
        asm volatile("s_waitcnt lgkmcnt(0)" ::: "memory");   // all my buf[kt&1] reads done
        asm volatile("s_waitcnt vmcnt(0)" ::: "memory");     // stage(kt+1) landed (2-tile slack)
        __builtin_amdgcn_s_barrier();
        if (kt < 70) stage(kt + 2);                          // overwrite just-freed buffer
        if (kt < 71) {
            const char* nb = (const char*)&lds[(kt + 1) & 1][0];
            RD_A(aC, nb, 0, sw0);
            RD_B(bC, nb, sw0);
        }
        __builtin_amdgcn_sched_barrier(0);
        MFMA16(aN, bN, 1);
    }

    // epilogue: out[b][o][p] = acc * inv_denom[b][o]
    const float* invb = invd + b * 512 + o0 + wm * 128;
    float* outb = out + ((size_t)b * 512 + o0 + wm * 128) * 4096 + p0 + wn * 64;
#pragma unroll
    for (int mi = 0; mi < 8; ++mi) {
#pragma unroll
        for (int r = 0; r < 4; ++r) {
            int m = mi * 16 + quad * 4 + r;
            float d = invb[m];
#pragma unroll
            for (int ni = 0; ni < 4; ++ni) {
                int n = ni * 16 + l15;
                outb[(size_t)m * 4096 + n] = acc[mi][ni][r] * d;
            }
        }
    }
}

extern "C" void kernel_launch(void* const* d_in, const int* in_sizes, int n_in,
                              void* d_out, int out_size, void* d_ws, size_t ws_size,
                              hipStream_t stream) {
    const float* x  = (const float*)d_in[0];   // (16,512,64,64)
    const float* w  = (const float*)d_in[1];   // (16,512)
    const float* cw = (const float*)d_in[2];   // (512,512,3,3)
    const float* lw = (const float*)d_in[3];   // (512,512)
    const float* lb = (const float*)d_in[4];   // (512,)
    float* out = (float*)d_out;

    char* ws = (char*)d_ws;
    float*    style = (float*)(ws + WS_STYLE);
    float*    invd  = (float*)(ws + WS_INVD);
    float*    wsq   = (float*)(ws + WS_WSQ);
    ushort_t* Aw    = (ushort_t*)(ws + WS_AW);
    ushort_t* Xp    = (ushort_t*)(ws + WS_XP);

    prep_fused1<<<3072, 256, 0, stream>>>(w, lw, lb, cw, style, Aw, wsq);
    prep_fused2<<<11280, 256, 0, stream>>>(wsq, style, invd, x, Xp);
    conv_gemm<<<512, 512, 0, stream>>>(Aw, Xp, invd, out);
}